// Round 6
// baseline (870.188 us; speedup 1.0000x reference)
//
#include <hip/hip_runtime.h>
#include <math.h>

#define BB 4
#define TT 4
#define CC 256
#define HH 30
#define WW 40
#define HWS (HH*WW)          // 1200
#define CHW (CC*HWS)         // 307200

typedef __attribute__((ext_vector_type(8))) _Float16 half8;
typedef __attribute__((ext_vector_type(4))) _Float16 half4;
typedef __attribute__((ext_vector_type(4))) float f32x4;
typedef __attribute__((ext_vector_type(16))) float f32x16;

// ---------------------------------------------------------------------------
// h0 = sum_t x[b,t,:,:,:]; c0 = h0
// ---------------------------------------------------------------------------
__global__ void init_hc(const float* __restrict__ x,
                        float* __restrict__ h, float* __restrict__ c) {
    int id = blockIdx.x * 256 + threadIdx.x;
    if (id >= BB * CHW) return;
    int b = id / CHW;
    int rem = id - b * CHW;
    float s = 0.f;
#pragma unroll
    for (int t = 0; t < TT; ++t)
        s += x[((size_t)b * TT + t) * CHW + rem];
    h[id] = s;
    c[id] = s;
}

// ---------------------------------------------------------------------------
// Pack weights to f16: layout [kg=k/8][Cout][k%8], k = src*2304 + tap*256 + ci
// ---------------------------------------------------------------------------
__global__ void pack_weights(const float* __restrict__ W1,
                             const float* __restrict__ W2,
                             _Float16* __restrict__ wt, int Cout) {
    int idx = blockIdx.x * 256 + threadIdx.x;
    if (idx >= 4608 * Cout) return;
    int k = idx / Cout;
    int n = idx - k * Cout;
    float v = (k < 2304) ? W1[(size_t)k * Cout + n]
                         : W2[(size_t)(k - 2304) * Cout + n];
    wt[((size_t)(k >> 3) * Cout + n) * 8 + (k & 7)] = (_Float16)v;
}

// ---------------------------------------------------------------------------
// 32x32x16 MFMA dual 3x3 conv, f16, z-split over the two sources:
//   z=0: partial = conv(in0*scale, W1) + b1 + b2 ; z=1: partial = conv(in1,W2)
// Block: M-tile 128 px (pixel-linear, 10 tiles/batch, last padded), 4 waves
// split M (32 px each); NW=2 n-tiles of 32 => block N=64. All waves share B.
// LDS: 6 halo rows x 42 px, 32 ci @ stride 80B (conflict-free b128 reads).
// Partials written f16 to out[z][B][Cout][HWS].
// ---------------------------------------------------------------------------
__global__ __launch_bounds__(256) void conv_mfma32(
    const float* __restrict__ in0, long bs0, const float* __restrict__ scale,
    const float* __restrict__ in1, long bs1,
    const _Float16* __restrict__ wt,
    const float* __restrict__ b1, const float* __restrict__ b2,
    _Float16* __restrict__ out, int Cout)
{
    __shared__ alignas(16) _Float16 s_a[252 * 40];   // [hpix][32ci], stride 40 halfs

    const int tid = threadIdx.x;
    const int l = tid & 63, wv = tid >> 6;
    const int kq = l >> 5;                 // k-half selector
    const int mb = blockIdx.x;             // 0..39
    const int b = mb / 10;
    const int mt = mb - b * 10;
    const int p0 = mt * 128;
    const int y_first = p0 / 40;
    const int n0 = blockIdx.y * 64;
    const int z = blockIdx.z;

    const float* inp = z ? (in1 + (size_t)b * bs1) : (in0 + (size_t)b * bs0);
    const float* scl = z ? nullptr : scale;

    // per-lane A-fragment pixel
    const int px = p0 + wv * 32 + (l & 31);
    const int ay = px / 40, ax = px - (px / 40) * 40;
    const int hbase = (ay - y_first) * 42 + ax;

    f32x16 acc[2];
#pragma unroll
    for (int nt = 0; nt < 2; ++nt) {
        float bias = z ? 0.f : (b1[n0 + nt * 32 + (l & 31)] + b2[n0 + nt * 32 + (l & 31)]);
#pragma unroll
        for (int j = 0; j < 16; ++j) acc[nt][j] = bias;
    }

    const half8* __restrict__ wp8 = (const half8*)wt;

    for (int ci0 = 0; ci0 < CC; ci0 += 32) {
        __syncthreads();
        // stage 6 rows x 42 px x 32 ci (8 ci per item, b128 writes)
        for (int i = tid; i < 1008; i += 256) {
            int hpix = i >> 2, cig = i & 3;
            int hrow = hpix / 42;
            int hcol = hpix - hrow * 42;
            int yy = y_first - 1 + hrow, xx = hcol - 1;
            half8 hv = {0, 0, 0, 0, 0, 0, 0, 0};
            if (yy >= 0 && yy < HH && xx >= 0 && xx < WW) {
                const float* p = inp + (size_t)(ci0 + cig * 8) * HWS + yy * WW + xx;
                float sc = scl ? scl[(size_t)b * HWS + yy * WW + xx] : 1.f;
#pragma unroll
                for (int j = 0; j < 8; ++j)
                    hv[j] = (_Float16)(p[(size_t)j * HWS] * sc);
            }
            *(half8*)&s_a[hpix * 40 + cig * 8] = hv;
        }
        __syncthreads();

        const int kgz = z * 288 + (ci0 >> 3);
#pragma unroll
        for (int tap = 0; tap < 9; ++tap) {
            const int dy = tap / 3, dx = tap - dy * 3;
            const int abase = (hbase + dy * 42 + dx) * 40 + kq * 8;
            const int kgt = kgz + tap * 32;
#pragma unroll
            for (int ks = 0; ks < 2; ++ks) {
                half8 af = *(const half8*)&s_a[abase + ks * 16];
                size_t wo = (size_t)(kgt + ks * 2 + kq) * Cout + n0 + (l & 31);
                half8 bf0 = wp8[wo];
                half8 bf1 = wp8[wo + 32];
                acc[0] = __builtin_amdgcn_mfma_f32_32x32x16_f16(af, bf0, acc[0], 0, 0, 0);
                acc[1] = __builtin_amdgcn_mfma_f32_32x32x16_f16(af, bf1, acc[1], 0, 0, 0);
            }
        }
    }

    // epilogue: C/D row = (reg&3) + 8*(reg>>2) + 4*(l>>5); col = l&31
#pragma unroll
    for (int nt = 0; nt < 2; ++nt) {
        int co = n0 + nt * 32 + (l & 31);
        _Float16* ob = out + ((size_t)(z * BB + b) * Cout + co) * HWS;
#pragma unroll
        for (int a4 = 0; a4 < 4; ++a4) {
            int pix = p0 + wv * 32 + a4 * 8 + kq * 4;
            if (pix < HWS) {
                half4 hv;
#pragma unroll
                for (int bi = 0; bi < 4; ++bi)
                    hv[bi] = (_Float16)acc[nt][a4 * 4 + bi];
                *(half4*)&ob[pix] = hv;
            }
        }
    }
}

// ---------------------------------------------------------------------------
// att = tanh(p0 + p1)   (f16 partials -> f32)
// ---------------------------------------------------------------------------
__global__ void add_tanh(const _Float16* __restrict__ a0,
                         const _Float16* __restrict__ a1,
                         float* __restrict__ o, int n) {
    int id = blockIdx.x * 256 + threadIdx.x;
    if (id < n) o[id] = tanhf((float)a0[id] + (float)a1[id]);
}

// ---------------------------------------------------------------------------
// K-split attention score partials over ca-chunks
// ---------------------------------------------------------------------------
__global__ __launch_bounds__(256) void att_e_part(
    const float* __restrict__ att, const float* __restrict__ Va,
    float* __restrict__ part)
{
    __shared__ float red[4][64];
    const int lane = threadIdx.x & 63, wv = threadIdx.x >> 6;
    const int p = blockIdx.x * 64 + lane;
    const int b = blockIdx.y, ch = blockIdx.z;
    const bool valid = (p < HWS);
    const int pc = valid ? p : 0;
    const int y = pc / WW, x = pc - (pc / WW) * WW;

    float acc = 0.f;
    if (valid) {
        const int ca0 = ch * 32 + wv * 8;
#pragma unroll
        for (int j = 0; j < 8; ++j) {
            const int ca = ca0 + j;
            const float* base = att + ((size_t)b * CC + ca) * HWS;
            const float* va = Va + ca;
#pragma unroll
            for (int dy = 0; dy < 3; ++dy) {
                int yy = y + dy - 1;
                if (yy < 0 || yy >= HH) continue;
#pragma unroll
                for (int dx = 0; dx < 3; ++dx) {
                    int xx = x + dx - 1;
                    if (xx < 0 || xx >= WW) continue;
                    acc = fmaf(base[yy * WW + xx], va[(dy * 3 + dx) * CC], acc);
                }
            }
        }
    }
    red[wv][lane] = acc;
    __syncthreads();
    if (wv == 0 && valid)
        part[((size_t)b * 8 + ch) * HWS + p] =
            red[0][lane] + red[1][lane] + red[2][lane] + red[3][lane];
}

// ---------------------------------------------------------------------------
// softmax over HW per batch, summing the 8 K-split partials first (in LDS)
// ---------------------------------------------------------------------------
__global__ __launch_bounds__(256) void softmax_kernel(
    const float* __restrict__ part, float* __restrict__ a)
{
    __shared__ float se[HWS];
    __shared__ float red[256];
    int b = blockIdx.x;
    int tid = threadIdx.x;

    for (int i = tid; i < HWS; i += 256) {
        float s = 0.f;
#pragma unroll
        for (int ch = 0; ch < 8; ++ch)
            s += part[((size_t)b * 8 + ch) * HWS + i];
        se[i] = s;
    }
    __syncthreads();

    float m = -1e30f;
    for (int i = tid; i < HWS; i += 256) m = fmaxf(m, se[i]);
    red[tid] = m;
    __syncthreads();
    for (int s = 128; s > 0; s >>= 1) {
        if (tid < s) red[tid] = fmaxf(red[tid], red[tid + s]);
        __syncthreads();
    }
    m = red[0];
    __syncthreads();

    float sum = 0.f;
    for (int i = tid; i < HWS; i += 256) {
        float v = expf(se[i] - m);
        se[i] = v;
        sum += v;
    }
    red[tid] = sum;
    __syncthreads();
    for (int s = 128; s > 0; s >>= 1) {
        if (tid < s) red[tid] += red[tid + s];
        __syncthreads();
    }
    float inv = 1.f / red[0];
    for (int i = tid; i < HWS; i += 256)
        a[(size_t)b * HWS + i] = se[i] * inv;
}

// ---------------------------------------------------------------------------
// LSTM gate update from two f16 partial buffers [B,4C,H,W]
// ---------------------------------------------------------------------------
__global__ void gate_update(const _Float16* __restrict__ g0,
                            const _Float16* __restrict__ g1,
                            float* __restrict__ c, float* __restrict__ h_out) {
    int id = blockIdx.x * 256 + threadIdx.x;
    if (id >= BB * CHW) return;
    int b = id / CHW;
    int rem = id - b * CHW;
    size_t gbase = (size_t)b * 4 * CHW + rem;
    float gi = (float)g0[gbase] + (float)g1[gbase];
    float gf = (float)g0[gbase + CHW] + (float)g1[gbase + CHW];
    float gc = (float)g0[gbase + 2 * (size_t)CHW] + (float)g1[gbase + 2 * (size_t)CHW];
    float go = (float)g0[gbase + 3 * (size_t)CHW] + (float)g1[gbase + 3 * (size_t)CHW];
    float i_ = 1.f / (1.f + expf(-gi));
    float f_ = 1.f / (1.f + expf(-gf));
    float o_ = 1.f / (1.f + expf(-go));
    float cn = f_ * c[id] + i_ * tanhf(gc);
    c[id] = cn;
    h_out[id] = o_ * tanhf(cn);
}

// ---------------------------------------------------------------------------
extern "C" void kernel_launch(void* const* d_in, const int* in_sizes, int n_in,
                              void* d_out, int out_size, void* d_ws, size_t ws_size,
                              hipStream_t stream) {
    const float* x   = (const float*)d_in[0];
    const float* Wa  = (const float*)d_in[1];
    const float* ba  = (const float*)d_in[2];
    const float* Ua  = (const float*)d_in[3];
    const float* bua = (const float*)d_in[4];
    const float* Va  = (const float*)d_in[5];
    const float* Wx  = (const float*)d_in[6];
    const float* bx  = (const float*)d_in[7];
    const float* Uh  = (const float*)d_in[8];
    const float* bh  = (const float*)d_in[9];
    float* out = (float*)d_out;

    char* wsb = (char*)d_ws;
    const size_t NCHW = (size_t)BB * CHW;
    _Float16* wtg = (_Float16*)wsb;               wsb += (size_t)4608 * 1024 * 2;
    _Float16* wta = (_Float16*)wsb;               wsb += (size_t)4608 * 256 * 2;
    float* h0    = (float*)wsb;                   wsb += NCHW * 4;
    float* h1    = (float*)wsb;                   wsb += NCHW * 4;
    float* cb    = (float*)wsb;                   wsb += NCHW * 4;
    _Float16* attp = (_Float16*)wsb;              wsb += 2 * NCHW * 2;   // z-stacked f16
    float* att   = (float*)wsb;                   wsb += NCHW * 4;
    _Float16* gp = (_Float16*)wsb;                wsb += 2 * 4 * NCHW * 2; // z-stacked f16
    float* part  = (float*)wsb;                   wsb += (size_t)BB * 8 * HWS * 4;
    float* a     = (float*)wsb;

    pack_weights<<<dim3((4608 * 1024 + 255) / 256), dim3(256), 0, stream>>>(
        Wx, Uh, wtg, 1024);
    pack_weights<<<dim3((4608 * 256 + 255) / 256), dim3(256), 0, stream>>>(
        Wa, Ua, wta, 256);

    const int n = (int)NCHW;
    init_hc<<<dim3((n + 255) / 256), dim3(256), 0, stream>>>(x, h0, cb);

    float* hbuf[2] = {h0, h1};
    const long XT_BS = (long)TT * CHW;
    const long H_BS  = (long)CHW;

    for (int t = 0; t < TT; ++t) {
        const float* xt = x + (size_t)t * CHW;
        float* hcur = hbuf[t & 1];
        float* hnext = (t == TT - 1) ? out : hbuf[(t + 1) & 1];

        // attention: attp[z=0]=conv(h,Wa)+biases ; attp[z=1]=conv(xt,Ua)
        conv_mfma32<<<dim3(40, 4, 2), dim3(256), 0, stream>>>(
            hcur, H_BS, nullptr, xt, XT_BS, wta, ba, bua, attp, 256);
        add_tanh<<<dim3((n + 255) / 256), dim3(256), 0, stream>>>(
            attp, attp + NCHW, att, n);

        // e-partials (K-split over ca) + softmax (sums partials)
        att_e_part<<<dim3(19, BB, 8), dim3(256), 0, stream>>>(att, Va, part);
        softmax_kernel<<<dim3(BB), dim3(256), 0, stream>>>(part, a);

        // gates: gp[z=0]=conv(xt*a,Wx)+biases ; gp[z=1]=conv(h,Uh)
        conv_mfma32<<<dim3(40, 16, 2), dim3(256), 0, stream>>>(
            xt, XT_BS, a, hcur, H_BS, wtg, bx, bh, gp, 1024);

        gate_update<<<dim3((n + 255) / 256), dim3(256), 0, stream>>>(
            gp, gp + 4 * NCHW, cb, hnext);
    }
}

// Round 7
// 685.805 us; speedup vs baseline: 1.2689x; 1.2689x over previous
//
#include <hip/hip_runtime.h>
#include <math.h>

#define BB 4
#define TT 4
#define CC 256
#define HH 30
#define WW 40
#define HWS (HH*WW)          // 1200
#define CHW (CC*HWS)         // 307200

typedef __attribute__((ext_vector_type(8))) _Float16 half8;
typedef __attribute__((ext_vector_type(4))) _Float16 half4;
typedef __attribute__((ext_vector_type(16))) float f32x16;

// ---------------------------------------------------------------------------
// h0 = sum_t x[b,t,:,:,:]; c0 = h0
// ---------------------------------------------------------------------------
__global__ void init_hc(const float* __restrict__ x,
                        float* __restrict__ h, float* __restrict__ c) {
    int id = blockIdx.x * 256 + threadIdx.x;
    if (id >= BB * CHW) return;
    int b = id / CHW;
    int rem = id - b * CHW;
    float s = 0.f;
#pragma unroll
    for (int t = 0; t < TT; ++t)
        s += x[((size_t)b * TT + t) * CHW + rem];
    h[id] = s;
    c[id] = s;
}

// ---------------------------------------------------------------------------
// Pack weights to f16: layout [kg=k/8][Cout][k%8], k = src*2304 + tap*256 + ci
// ---------------------------------------------------------------------------
__global__ void pack_weights(const float* __restrict__ W1,
                             const float* __restrict__ W2,
                             _Float16* __restrict__ wt, int Cout) {
    int idx = blockIdx.x * 256 + threadIdx.x;
    if (idx >= 4608 * Cout) return;
    int k = idx / Cout;
    int n = idx - k * Cout;
    float v = (k < 2304) ? W1[(size_t)k * Cout + n]
                         : W2[(size_t)(k - 2304) * Cout + n];
    wt[((size_t)(k >> 3) * Cout + n) * 8 + (k & 7)] = (_Float16)v;
}

// ---------------------------------------------------------------------------
// 32x32x16 MFMA dual 3x3 conv, f16.
// blockIdx.z = src*ZH + zi; zi selects a CC/ZH ci-slice (K-split).
//   z==0 folds biases; partials stacked at out + z*B*Cout*HWS (f16).
// Block: M=128 px (pixel-linear) x N=128 co. 4 waves in 2x2: each wave
// owns 2 m-tiles x 2 n-tiles => per (tap,ks): 2 A-reads + 2 B-loads +
// 4 MFMAs. B redundancy 2x/block; A via LDS (6 halo rows x 42 x 32ci).
// ---------------------------------------------------------------------------
template<int ZH>
__global__ __launch_bounds__(256) void conv_mfma32(
    const float* __restrict__ in0, long bs0, const float* __restrict__ scale,
    const float* __restrict__ in1, long bs1,
    const _Float16* __restrict__ wt,
    const float* __restrict__ b1, const float* __restrict__ b2,
    _Float16* __restrict__ out, int Cout)
{
    __shared__ alignas(16) _Float16 s_a[252 * 40];   // [hpix][32ci]

    const int tid = threadIdx.x;
    const int l = tid & 63, wv = tid >> 6;
    const int kq = l >> 5, ln = l & 31;
    const int mb = blockIdx.x;             // 0..39
    const int b = mb / 10;
    const int mt = mb - b * 10;
    const int p0 = mt * 128;
    const int y_first = p0 / 40;
    const int n0 = blockIdx.y * 128;
    const int z = blockIdx.z;
    const int src = z / ZH, zi = z - src * ZH;
    const int ci_begin = zi * (CC / ZH);

    const int mt_b = (wv >> 1) * 2;        // wave's m-tile base (0 or 2)
    const int colb = n0 + (wv & 1) * 64 + ln;   // wave's first B column

    const float* inp = src ? (in1 + (size_t)b * bs1) : (in0 + (size_t)b * bs0);
    const float* scl = src ? nullptr : scale;

    // A-fragment halo bases for the wave's two m-tiles
    int hb[2];
#pragma unroll
    for (int m = 0; m < 2; ++m) {
        int px = p0 + (mt_b + m) * 32 + ln;
        hb[m] = (px / 40 - y_first) * 42 + (px - (px / 40) * 40);
    }

    f32x16 acc[2][2];
#pragma unroll
    for (int n = 0; n < 2; ++n) {
        float bias = (z == 0) ? (b1[colb + n * 32] + b2[colb + n * 32]) : 0.f;
#pragma unroll
        for (int m = 0; m < 2; ++m)
#pragma unroll
            for (int j = 0; j < 16; ++j) acc[m][n][j] = bias;
    }

    const half8* __restrict__ wp8 = (const half8*)wt;

#pragma unroll
    for (int c8 = 0; c8 < CC / ZH; c8 += 32) {
        const int ci0 = ci_begin + c8;
        __syncthreads();
        // stage 6 rows x 42 px x 32 ci (8 ci per item, b128 writes)
        for (int i = tid; i < 1008; i += 256) {
            int hpix = i >> 2, cig = i & 3;
            int hrow = hpix / 42;
            int hcol = hpix - hrow * 42;
            int yy = y_first - 1 + hrow, xx = hcol - 1;
            half8 hv = {0, 0, 0, 0, 0, 0, 0, 0};
            if (yy >= 0 && yy < HH && xx >= 0 && xx < WW) {
                const float* p = inp + (size_t)(ci0 + cig * 8) * HWS + yy * WW + xx;
                float sc = scl ? scl[(size_t)b * HWS + yy * WW + xx] : 1.f;
#pragma unroll
                for (int j = 0; j < 8; ++j)
                    hv[j] = (_Float16)(p[(size_t)j * HWS] * sc);
            }
            *(half8*)&s_a[hpix * 40 + cig * 8] = hv;
        }
        __syncthreads();

        const int kgz = src * 288 + (ci0 >> 3);
#pragma unroll
        for (int tap = 0; tap < 9; ++tap) {
            const int dy = tap / 3, dx = tap - dy * 3;
            const int kgt = kgz + tap * 32;
#pragma unroll
            for (int ks = 0; ks < 2; ++ks) {
                half8 af0 = *(const half8*)&s_a[(hb[0] + dy * 42 + dx) * 40 + ks * 16 + kq * 8];
                half8 af1 = *(const half8*)&s_a[(hb[1] + dy * 42 + dx) * 40 + ks * 16 + kq * 8];
                size_t wo = (size_t)(kgt + ks * 2 + kq) * Cout + colb;
                half8 bf0 = wp8[wo];
                half8 bf1 = wp8[wo + 32];
                acc[0][0] = __builtin_amdgcn_mfma_f32_32x32x16_f16(af0, bf0, acc[0][0], 0, 0, 0);
                acc[0][1] = __builtin_amdgcn_mfma_f32_32x32x16_f16(af0, bf1, acc[0][1], 0, 0, 0);
                acc[1][0] = __builtin_amdgcn_mfma_f32_32x32x16_f16(af1, bf0, acc[1][0], 0, 0, 0);
                acc[1][1] = __builtin_amdgcn_mfma_f32_32x32x16_f16(af1, bf1, acc[1][1], 0, 0, 0);
            }
        }
    }

    // epilogue: C/D row = (reg&3) + 8*(reg>>2) + 4*kq; col = ln
#pragma unroll
    for (int m = 0; m < 2; ++m) {
#pragma unroll
        for (int n = 0; n < 2; ++n) {
            int co = colb + n * 32;
            _Float16* ob = out + ((size_t)(z * BB + b) * Cout + co) * HWS;
#pragma unroll
            for (int a4 = 0; a4 < 4; ++a4) {
                int pix = p0 + (mt_b + m) * 32 + a4 * 8 + kq * 4;
                if (pix < HWS) {
                    half4 hv;
#pragma unroll
                    for (int bi = 0; bi < 4; ++bi)
                        hv[bi] = (_Float16)acc[m][n][a4 * 4 + bi];
                    *(half4*)&ob[pix] = hv;
                }
            }
        }
    }
}

// ---------------------------------------------------------------------------
// att = tanh(sum of 8 f16 partials)
// ---------------------------------------------------------------------------
__global__ void add_tanh8(const _Float16* __restrict__ p,
                          float* __restrict__ o, int n, long stride) {
    int id = blockIdx.x * 256 + threadIdx.x;
    if (id >= n) return;
    float s = 0.f;
#pragma unroll
    for (int j = 0; j < 8; ++j)
        s += (float)p[(size_t)j * stride + id];
    o[id] = tanhf(s);
}

// ---------------------------------------------------------------------------
// K-split attention score partials over ca-chunks
// ---------------------------------------------------------------------------
__global__ __launch_bounds__(256) void att_e_part(
    const float* __restrict__ att, const float* __restrict__ Va,
    float* __restrict__ part)
{
    __shared__ float red[4][64];
    const int lane = threadIdx.x & 63, wv = threadIdx.x >> 6;
    const int p = blockIdx.x * 64 + lane;
    const int b = blockIdx.y, ch = blockIdx.z;
    const bool valid = (p < HWS);
    const int pc = valid ? p : 0;
    const int y = pc / WW, x = pc - (pc / WW) * WW;

    float acc = 0.f;
    if (valid) {
        const int ca0 = ch * 32 + wv * 8;
#pragma unroll
        for (int j = 0; j < 8; ++j) {
            const int ca = ca0 + j;
            const float* base = att + ((size_t)b * CC + ca) * HWS;
            const float* va = Va + ca;
#pragma unroll
            for (int dy = 0; dy < 3; ++dy) {
                int yy = y + dy - 1;
                if (yy < 0 || yy >= HH) continue;
#pragma unroll
                for (int dx = 0; dx < 3; ++dx) {
                    int xx = x + dx - 1;
                    if (xx < 0 || xx >= WW) continue;
                    acc = fmaf(base[yy * WW + xx], va[(dy * 3 + dx) * CC], acc);
                }
            }
        }
    }
    red[wv][lane] = acc;
    __syncthreads();
    if (wv == 0 && valid)
        part[((size_t)b * 8 + ch) * HWS + p] =
            red[0][lane] + red[1][lane] + red[2][lane] + red[3][lane];
}

// ---------------------------------------------------------------------------
// softmax over HW per batch, summing the 8 K-split partials first (in LDS)
// ---------------------------------------------------------------------------
__global__ __launch_bounds__(256) void softmax_kernel(
    const float* __restrict__ part, float* __restrict__ a)
{
    __shared__ float se[HWS];
    __shared__ float red[256];
    int b = blockIdx.x;
    int tid = threadIdx.x;

    for (int i = tid; i < HWS; i += 256) {
        float s = 0.f;
#pragma unroll
        for (int ch = 0; ch < 8; ++ch)
            s += part[((size_t)b * 8 + ch) * HWS + i];
        se[i] = s;
    }
    __syncthreads();

    float m = -1e30f;
    for (int i = tid; i < HWS; i += 256) m = fmaxf(m, se[i]);
    red[tid] = m;
    __syncthreads();
    for (int s = 128; s > 0; s >>= 1) {
        if (tid < s) red[tid] = fmaxf(red[tid], red[tid + s]);
        __syncthreads();
    }
    m = red[0];
    __syncthreads();

    float sum = 0.f;
    for (int i = tid; i < HWS; i += 256) {
        float v = expf(se[i] - m);
        se[i] = v;
        sum += v;
    }
    red[tid] = sum;
    __syncthreads();
    for (int s = 128; s > 0; s >>= 1) {
        if (tid < s) red[tid] += red[tid + s];
        __syncthreads();
    }
    float inv = 1.f / red[0];
    for (int i = tid; i < HWS; i += 256)
        a[(size_t)b * HWS + i] = se[i] * inv;
}

// ---------------------------------------------------------------------------
// LSTM gate update from two f16 partial buffers [B,4C,H,W]
// ---------------------------------------------------------------------------
__global__ void gate_update(const _Float16* __restrict__ g0,
                            const _Float16* __restrict__ g1,
                            float* __restrict__ c, float* __restrict__ h_out) {
    int id = blockIdx.x * 256 + threadIdx.x;
    if (id >= BB * CHW) return;
    int b = id / CHW;
    int rem = id - b * CHW;
    size_t gbase = (size_t)b * 4 * CHW + rem;
    float gi = (float)g0[gbase] + (float)g1[gbase];
    float gf = (float)g0[gbase + CHW] + (float)g1[gbase + CHW];
    float gc = (float)g0[gbase + 2 * (size_t)CHW] + (float)g1[gbase + 2 * (size_t)CHW];
    float go = (float)g0[gbase + 3 * (size_t)CHW] + (float)g1[gbase + 3 * (size_t)CHW];
    float i_ = 1.f / (1.f + expf(-gi));
    float f_ = 1.f / (1.f + expf(-gf));
    float o_ = 1.f / (1.f + expf(-go));
    float cn = f_ * c[id] + i_ * tanhf(gc);
    c[id] = cn;
    h_out[id] = o_ * tanhf(cn);
}

// ---------------------------------------------------------------------------
extern "C" void kernel_launch(void* const* d_in, const int* in_sizes, int n_in,
                              void* d_out, int out_size, void* d_ws, size_t ws_size,
                              hipStream_t stream) {
    const float* x   = (const float*)d_in[0];
    const float* Wa  = (const float*)d_in[1];
    const float* ba  = (const float*)d_in[2];
    const float* Ua  = (const float*)d_in[3];
    const float* bua = (const float*)d_in[4];
    const float* Va  = (const float*)d_in[5];
    const float* Wx  = (const float*)d_in[6];
    const float* bx  = (const float*)d_in[7];
    const float* Uh  = (const float*)d_in[8];
    const float* bh  = (const float*)d_in[9];
    float* out = (float*)d_out;

    char* wsb = (char*)d_ws;
    const size_t NCHW = (size_t)BB * CHW;
    _Float16* wtg = (_Float16*)wsb;               wsb += (size_t)4608 * 1024 * 2;
    _Float16* wta = (_Float16*)wsb;               wsb += (size_t)4608 * 256 * 2;
    float* h0    = (float*)wsb;                   wsb += NCHW * 4;
    float* h1    = (float*)wsb;                   wsb += NCHW * 4;
    float* cb    = (float*)wsb;                   wsb += NCHW * 4;
    _Float16* attp = (_Float16*)wsb;              wsb += 8 * NCHW * 2;     // 8 z-bufs f16
    float* att   = (float*)wsb;                   wsb += NCHW * 4;
    _Float16* gp = (_Float16*)wsb;                wsb += 2 * 4 * NCHW * 2; // 2 z-bufs f16
    float* part  = (float*)wsb;                   wsb += (size_t)BB * 8 * HWS * 4;
    float* a     = (float*)wsb;

    pack_weights<<<dim3((4608 * 1024 + 255) / 256), dim3(256), 0, stream>>>(
        Wx, Uh, wtg, 1024);
    pack_weights<<<dim3((4608 * 256 + 255) / 256), dim3(256), 0, stream>>>(
        Wa, Ua, wta, 256);

    const int n = (int)NCHW;
    init_hc<<<dim3((n + 255) / 256), dim3(256), 0, stream>>>(x, h0, cb);

    float* hbuf[2] = {h0, h1};
    const long XT_BS = (long)TT * CHW;
    const long H_BS  = (long)CHW;

    for (int t = 0; t < TT; ++t) {
        const float* xt = x + (size_t)t * CHW;
        float* hcur = hbuf[t & 1];
        float* hnext = (t == TT - 1) ? out : hbuf[(t + 1) & 1];

        // attention partials (ZH=4 -> 8 z-bufs), then att = tanh(sum)
        conv_mfma32<4><<<dim3(40, 2, 8), dim3(256), 0, stream>>>(
            hcur, H_BS, nullptr, xt, XT_BS, wta, ba, bua, attp, 256);
        add_tanh8<<<dim3((n + 255) / 256), dim3(256), 0, stream>>>(
            attp, att, n, (long)NCHW);

        // e-partials (K-split over ca) + softmax (sums partials)
        att_e_part<<<dim3(19, BB, 8), dim3(256), 0, stream>>>(att, Va, part);
        softmax_kernel<<<dim3(BB), dim3(256), 0, stream>>>(part, a);

        // gates: gp[z=0]=conv(xt*a,Wx)+biases ; gp[z=1]=conv(h,Uh)
        conv_mfma32<1><<<dim3(40, 8, 2), dim3(256), 0, stream>>>(
            xt, XT_BS, a, hcur, H_BS, wtg, bx, bh, gp, 1024);

        gate_update<<<dim3((n + 255) / 256), dim3(256), 0, stream>>>(
            gp, gp + 4 * NCHW, cb, hnext);
    }
}